// Round 12
// baseline (354.951 us; speedup 1.0000x reference)
//
#include <hip/hip_runtime.h>
#include <math.h>

typedef __bf16 bf16x8 __attribute__((ext_vector_type(8)));
typedef float f32x16 __attribute__((ext_vector_type(16)));

// ---------------- helpers ----------------
__device__ __forceinline__ unsigned short f2bf(float f) {
  union { float f; unsigned int u; } v; v.f = f;
  unsigned int r = (v.u + 0x7FFFu + ((v.u >> 16) & 1u)) >> 16;
  return (unsigned short)r;
}
__device__ __forceinline__ float bf2f(unsigned short u) {
  union { unsigned int u; float f; } v; v.u = ((unsigned int)u) << 16;
  return v.f;
}
// unpack 2 bf16 from one u32 (memory order: low half = even element)
__device__ __forceinline__ void bf2x(unsigned int u, float& lo, float& hi) {
  union { unsigned int u; float f; } a, b;
  a.u = u << 16; b.u = u & 0xFFFF0000u;
  lo = a.f; hi = b.f;
}
// async global->LDS 16B copy (global_load_lds_dwordx4)
__device__ __forceinline__ void gload16(const void* g, void* l) {
  __builtin_amdgcn_global_load_lds(
      (__attribute__((address_space(1))) void*)const_cast<void*>(g),
      (__attribute__((address_space(3))) void*)l, 16, 0, 0);
}

// ---------------- setup kernels ----------------
__global__ void k_init(int* cnt, int* meta, int N) {
  int i = blockIdx.x * blockDim.x + threadIdx.x;
  if (i < N) cnt[i] = 0;
  if (i < 32) meta[i] = 0;
}

__global__ __launch_bounds__(256) void k_scanA(const int* __restrict__ cnt,
                                               int* __restrict__ incl,
                                               int* __restrict__ bsums, int N) {
  __shared__ int s[1024];
  int base = blockIdx.x * 1024;
  #pragma unroll
  for (int t = 0; t < 4; ++t) {
    int i = threadIdx.x + t * 256;
    int idx = base + i;
    s[i] = (idx < N) ? cnt[idx] : 0;
  }
  __syncthreads();
  for (int d = 1; d < 1024; d <<= 1) {
    int v[4];
    #pragma unroll
    for (int t = 0; t < 4; ++t) {
      int i = threadIdx.x + t * 256;
      v[t] = (i >= d) ? s[i - d] : 0;
    }
    __syncthreads();
    #pragma unroll
    for (int t = 0; t < 4; ++t) {
      int i = threadIdx.x + t * 256;
      s[i] += v[t];
    }
    __syncthreads();
  }
  #pragma unroll
  for (int t = 0; t < 4; ++t) {
    int i = threadIdx.x + t * 256;
    int idx = base + i;
    if (idx < N) incl[idx] = s[i];
  }
  if (threadIdx.x == 0) bsums[blockIdx.x] = s[1023];
}

__global__ __launch_bounds__(256) void k_scanB(const int* __restrict__ bsums,
                                               int* __restrict__ boff, int nb) {
  __shared__ int s[1024];
  #pragma unroll
  for (int t = 0; t < 4; ++t) {
    int i = threadIdx.x + t * 256;
    s[i] = (i < nb) ? bsums[i] : 0;
  }
  __syncthreads();
  for (int d = 1; d < 1024; d <<= 1) {
    int v[4];
    #pragma unroll
    for (int t = 0; t < 4; ++t) {
      int i = threadIdx.x + t * 256;
      v[t] = (i >= d) ? s[i - d] : 0;
    }
    __syncthreads();
    #pragma unroll
    for (int t = 0; t < 4; ++t) {
      int i = threadIdx.x + t * 256;
      s[i] += v[t];
    }
    __syncthreads();
  }
  #pragma unroll
  for (int t = 0; t < 4; ++t) {
    int i = threadIdx.x + t * 256;
    if (i < nb) boff[i] = (i == 0) ? 0 : s[i - 1];
  }
}

// scanC + fused offs (meta hist is final: gate kernel completed before scanA)
__global__ void k_scanC(const int* __restrict__ cnt, const int* __restrict__ incl,
                        const int* __restrict__ boff, int* __restrict__ rowptr,
                        int* __restrict__ cursor, float* __restrict__ dinv,
                        int* __restrict__ meta, int N, int E) {
  int i = blockIdx.x * blockDim.x + threadIdx.x;
  if (i < N) {
    int ex = incl[i] - cnt[i] + boff[i >> 10];
    rowptr[i] = ex;
    cursor[i] = ex;
    dinv[i] = rsqrtf((float)(cnt[i] + 1));
    if (i == 0) rowptr[N] = E;
  }
  if (blockIdx.x == 0 && threadIdx.x == 0) {
    int* hist = meta;
    int* eoff = meta + 4;
    int* toff = meta + 9;
    int* ecur = meta + 14;
    int s = 0, t = 0;
    eoff[0] = 0; toff[0] = 0;
    for (int e = 0; e < 4; ++e) {
      s += hist[e];
      eoff[e + 1] = s;
      t += (hist[e] + 127) / 128;
      toff[e + 1] = t;
      ecur[e] = eoff[e];
    }
  }
}

// scatter edge -> csr2 {row, dinv[row]}; appended blocks do binscatter
__global__ __launch_bounds__(256) void k_scatter(const int* __restrict__ row,
                                                 const int* __restrict__ col,
                                                 int* __restrict__ cursor,
                                                 const float* __restrict__ dinv,
                                                 int2* __restrict__ csr2, int E,
                                                 const int* __restrict__ eidx,
                                                 int* __restrict__ meta,
                                                 int* __restrict__ perm, int N, int scatB) {
  int tid = threadIdx.x;
  if (blockIdx.x < (unsigned)scatB) {
    int e = blockIdx.x * 256 + tid;
    if (e < E) {
      int c = col[e];
      int r = row[e];
      int p = atomicAdd(&cursor[c], 1);
      csr2[p] = make_int2(r, __float_as_int(dinv[r]));
    }
    return;
  }
  // ---- binscatter (needs offs: done in k_scanC, prior launch) ----
  __shared__ int lhist[4];
  __shared__ int lbase[4];
  if (tid < 4) lhist[tid] = 0;
  __syncthreads();
  int n = (blockIdx.x - scatB) * 256 + tid;
  int e = 0, lrank = 0;
  bool valid = (n < N);
  if (valid) {
    e = eidx[n];
    lrank = atomicAdd(&lhist[e], 1);
  }
  __syncthreads();
  if (tid < 4) {
    int c = lhist[tid];
    lbase[tid] = (c > 0) ? atomicAdd(&meta[14 + tid], c) : 0;
  }
  __syncthreads();
  if (valid) perm[lbase[e] + lrank] = n;
}

// ---------------- fused gate (+bf16 cast of x) / degree-count / weight-pack ----------------
// Roles INTERLEAVED across the grid so count's atomic latency overlaps gate's streaming:
// within [0, 3*usedC): b%3==2 -> count(b/3), else gate(2*(b/3)+b%3); leftovers appended; pack last.
__global__ __launch_bounds__(256) void k_gate(const float* __restrict__ x,
                                              const float* __restrict__ wg,
                                              int* __restrict__ eidx,
                                              int* __restrict__ meta,
                                              unsigned short* __restrict__ xb,
                                              const int* __restrict__ col,
                                              int* __restrict__ cnt,
                                              const float* __restrict__ ew,
                                              unsigned short* __restrict__ ewb,
                                              const float* __restrict__ w2,
                                              unsigned short* __restrict__ w2b,
                                              int N, int E, int gateB, int cntB) {
  int tid = threadIdx.x;
  int b = blockIdx.x;
  int usedC = min(cntB, gateB / 2);
  int mix3 = 3 * usedC;
  int role, idx;                     // 0=gate 1=count 2=pack
  if (b < mix3) {
    if ((b % 3) == 2) { role = 1; idx = b / 3; }
    else              { role = 0; idx = (b / 3) * 2 + (b % 3); }
  } else {
    int r = b - mix3;
    int gLeft = gateB - 2 * usedC;
    if (r < gLeft) { role = 0; idx = 2 * usedC + r; }
    else {
      r -= gLeft;
      int cLeft = cntB - usedC;
      if (r < cLeft) { role = 1; idx = usedC + r; }
      else           { role = 2; idx = r - cLeft; }
    }
  }

  if (role == 1) {                   // ---- degree count ----
    int e = idx * 256 + tid;
    if (e < E) atomicAdd(&cnt[col[e]], 1);
    return;
  }
  if (role == 2) {                   // ---- weight pack ----
    if (idx < 256) {                 // ew: idx = e*64 + kc
      int n = tid;
      int eidx2 = idx >> 6, kc = idx & 63;
      const float* src = ew + ((size_t)eidx2 * 512 + (size_t)kc * 8) * 256 + n;
      unsigned short tmp[8];
      #pragma unroll
      for (int ke = 0; ke < 8; ++ke) tmp[ke] = f2bf(src[(size_t)ke * 256]);
      *(uint4*)(ewb + ((size_t)idx * 256 + n) * 8) = *(const uint4*)tmp;
    } else {                         // w2: kc = idx-256 in 0..31
      int kc = idx - 256;
      if (tid < 64) {
        const float* src = w2 + (size_t)kc * 8 * 64 + tid;
        unsigned short tmp[8];
        #pragma unroll
        for (int ke = 0; ke < 8; ++ke) tmp[ke] = f2bf(src[(size_t)ke * 64]);
        *(uint4*)(w2b + ((size_t)kc * 64 + tid) * 8) = *(const uint4*)tmp;
      }
    }
    return;
  }

  // ---- gating: wg transposed in LDS; 8 independent x loads up front ----
  __shared__ float wgT[4][512];
  __shared__ int lhist[4];
  if (tid < 4) lhist[tid] = 0;
  {
    int r0 = tid * 2;
    float4 wa = *(const float4*)(wg + 4 * r0);
    float4 wb = *(const float4*)(wg + 4 * (r0 + 1));
    wgT[0][r0] = wa.x; wgT[1][r0] = wa.y; wgT[2][r0] = wa.z; wgT[3][r0] = wa.w;
    wgT[0][r0 + 1] = wb.x; wgT[1][r0 + 1] = wb.y; wgT[2][r0 + 1] = wb.z; wgT[3][r0 + 1] = wb.w;
  }
  __syncthreads();
  int node = idx * 16 + (tid >> 4);
  int sl = tid & 15;
  if (node < N) {
    const float* xr = x + (size_t)node * 512;
    unsigned short* xbr = xb + (size_t)node * 512;
    float4 xv[8];
    #pragma unroll
    for (int j = 0; j < 8; ++j) xv[j] = *(const float4*)(xr + 4 * (sl + 16 * j));
    #pragma unroll
    for (int j = 0; j < 8; ++j) {
      ushort4 ov;
      ov.x = f2bf(xv[j].x); ov.y = f2bf(xv[j].y); ov.z = f2bf(xv[j].z); ov.w = f2bf(xv[j].w);
      *(ushort4*)(xbr + 4 * (sl + 16 * j)) = ov;
    }
    float l0 = 0.f, l1 = 0.f, l2 = 0.f, l3 = 0.f;
    #pragma unroll
    for (int j = 0; j < 8; ++j) {
      int k0 = 4 * (sl + 16 * j);
      float4 w0 = *(const float4*)&wgT[0][k0];
      float4 w1 = *(const float4*)&wgT[1][k0];
      float4 w2v = *(const float4*)&wgT[2][k0];
      float4 w3 = *(const float4*)&wgT[3][k0];
      l0 += xv[j].x * w0.x + xv[j].y * w0.y + xv[j].z * w0.z + xv[j].w * w0.w;
      l1 += xv[j].x * w1.x + xv[j].y * w1.y + xv[j].z * w1.z + xv[j].w * w1.w;
      l2 += xv[j].x * w2v.x + xv[j].y * w2v.y + xv[j].z * w2v.z + xv[j].w * w2v.w;
      l3 += xv[j].x * w3.x + xv[j].y * w3.y + xv[j].z * w3.z + xv[j].w * w3.w;
    }
    #pragma unroll
    for (int off = 8; off > 0; off >>= 1) {
      l0 += __shfl_xor(l0, off, 64);
      l1 += __shfl_xor(l1, off, 64);
      l2 += __shfl_xor(l2, off, 64);
      l3 += __shfl_xor(l3, off, 64);
    }
    if (sl == 0) {
      int a = 0; float best = l0;
      if (l1 > best) { best = l1; a = 1; }
      if (l2 > best) { best = l2; a = 2; }
      if (l3 > best) { best = l3; a = 3; }
      eidx[node] = a;
      atomicAdd(&lhist[a], 1);
    }
  }
  __syncthreads();
  if (tid < 4 && lhist[tid] > 0) atomicAdd(&meta[tid], lhist[tid]);
}

// ---------------- expert GEMM: bf16 MFMA 32x32x16, block tile 128x256 ----------------
__global__ __launch_bounds__(512, 2) void k_gemm1(const unsigned short* __restrict__ xb,
                                                  const unsigned short* __restrict__ ewb,
                                                  const float* __restrict__ eb,
                                                  const int* __restrict__ perm,
                                                  const int* __restrict__ meta,
                                                  unsigned short* __restrict__ h1) {
  __shared__ __align__(16) unsigned short A_lds[8192];    // [kcl 0..7][i 0..127][ke 0..7]
  __shared__ __align__(16) unsigned short B_lds[16384];   // [kcl 0..7][n 0..255][ke 0..7]
  __shared__ int sperm[128];
  const int* eoff = meta + 4;
  const int* toff = meta + 9;
  int v = blockIdx.x;
  if (v >= toff[4]) return;
  int e = 0;
  while (v >= toff[e + 1]) ++e;
  int m0 = eoff[e] + (v - toff[e]) * 128;
  int mEnd = eoff[e + 1];
  int tid = threadIdx.x;

  if (tid < 128) {
    int m = m0 + tid;
    sperm[tid] = perm[(m < mEnd) ? m : (mEnd - 1)];
  }
  __syncthreads();

  int wave = tid >> 6, lane = tid & 63;
  int wr = wave >> 2, wc = wave & 3;
  int hi = lane >> 5, lo = lane & 31;
  int r128 = tid & 127;

  f32x16 acc[2][2];
  #pragma unroll
  for (int mi = 0; mi < 2; ++mi)
    #pragma unroll
    for (int ni = 0; ni < 2; ++ni)
      #pragma unroll
      for (int r = 0; r < 16; ++r) acc[mi][ni][r] = 0.f;

  const unsigned short* arow = xb + (size_t)sperm[r128] * 512;
  int kclA = tid >> 7;  // 0..3
  const uint4* ebase = (const uint4*)(ewb + (size_t)e * 64 * 2048);

  for (int k0 = 0; k0 < 512; k0 += 64) {
    __syncthreads();  // previous chunk's compute done before LDS overwrite
    gload16(arow + k0 + kclA * 8,       &A_lds[((size_t)kclA * 128 + r128) * 8]);
    gload16(arow + k0 + (kclA + 4) * 8, &A_lds[((size_t)(kclA + 4) * 128 + r128) * 8]);
    const uint4* bsrc = ebase + (size_t)(k0 >> 3) * 256;
    gload16(bsrc + tid,        &B_lds[((size_t)0 * 512 + tid) * 8]);
    gload16(bsrc + 512 + tid,  &B_lds[((size_t)1 * 512 + tid) * 8]);
    gload16(bsrc + 1024 + tid, &B_lds[((size_t)2 * 512 + tid) * 8]);
    gload16(bsrc + 1536 + tid, &B_lds[((size_t)3 * 512 + tid) * 8]);
    __syncthreads();  // vmcnt(0) drain -> LDS ready
    #pragma unroll
    for (int s = 0; s < 4; ++s) {
      int kcl = s * 2 + hi;
      bf16x8 a0f = *(const bf16x8*)&A_lds[((size_t)kcl * 128 + wr * 64 + lo) * 8];
      bf16x8 a1f = *(const bf16x8*)&A_lds[((size_t)kcl * 128 + wr * 64 + 32 + lo) * 8];
      bf16x8 b0f = *(const bf16x8*)&B_lds[((size_t)kcl * 256 + wc * 64 + lo) * 8];
      bf16x8 b1f = *(const bf16x8*)&B_lds[((size_t)kcl * 256 + wc * 64 + 32 + lo) * 8];
      acc[0][0] = __builtin_amdgcn_mfma_f32_32x32x16_bf16(a0f, b0f, acc[0][0], 0, 0, 0);
      acc[0][1] = __builtin_amdgcn_mfma_f32_32x32x16_bf16(a0f, b1f, acc[0][1], 0, 0, 0);
      acc[1][0] = __builtin_amdgcn_mfma_f32_32x32x16_bf16(a1f, b0f, acc[1][0], 0, 0, 0);
      acc[1][1] = __builtin_amdgcn_mfma_f32_32x32x16_bf16(a1f, b1f, acc[1][1], 0, 0, 0);
    }
  }

  // epilogue: bias + scatter rows as bf16. C/D: col=lane&31, row=(reg&3)+8*(reg>>2)+4*(lane>>5)
  #pragma unroll
  for (int ni = 0; ni < 2; ++ni) {
    int col = wc * 64 + ni * 32 + lo;
    float bias = eb[e * 256 + col];
    #pragma unroll
    for (int mi = 0; mi < 2; ++mi) {
      #pragma unroll
      for (int q = 0; q < 4; ++q) {
        #pragma unroll
        for (int j = 0; j < 4; ++j) {
          int r = j + 8 * q + 4 * hi;
          int lrow = wr * 64 + mi * 32 + r;
          if (m0 + lrow < mEnd) {
            h1[(size_t)sperm[lrow] * 256 + col] = f2bf(acc[mi][ni][q * 4 + j] + bias);
          }
        }
      }
    }
  }
}

// ---------------- propagate 1 (256 feat, bf16): 32 lanes/row, 8 rows/block ----------------
__global__ __launch_bounds__(256) void k_prop1(const unsigned short* __restrict__ h1,
                                               const int* __restrict__ rowptr,
                                               const int2* __restrict__ csr2,
                                               const float* __restrict__ dinv,
                                               const float* __restrict__ bias1,
                                               unsigned short* __restrict__ hrelu, int N) {
  int tid = threadIdx.x;
  int c = blockIdx.x * 8 + (tid >> 5);
  int l = tid & 31;                        // 8 features per lane
  if (c >= N) return;
  float dc = dinv[c];
  const uint4* hr = (const uint4*)h1;      // row = 32 uint4
  uint4 sv = hr[(size_t)c * 32 + l];
  float slf = dc * dc;
  float a0, a1, a2, a3, a4, a5, a6, a7;
  {
    float lo, hi;
    bf2x(sv.x, lo, hi); a0 = lo * slf; a1 = hi * slf;
    bf2x(sv.y, lo, hi); a2 = lo * slf; a3 = hi * slf;
    bf2x(sv.z, lo, hi); a4 = lo * slf; a5 = hi * slf;
    bf2x(sv.w, lo, hi); a6 = lo * slf; a7 = hi * slf;
  }
  int jb = rowptr[c], je = rowptr[c + 1];
  int j = jb;
  #define ACC8(v, s) { float lo, hi; \
    bf2x((v).x, lo, hi); a0 += lo * (s); a1 += hi * (s); \
    bf2x((v).y, lo, hi); a2 += lo * (s); a3 += hi * (s); \
    bf2x((v).z, lo, hi); a4 += lo * (s); a5 += hi * (s); \
    bf2x((v).w, lo, hi); a6 += lo * (s); a7 += hi * (s); }
  for (; j + 7 < je; j += 8) {
    int2 rc[8];
    #pragma unroll
    for (int t = 0; t < 8; ++t) rc[t] = csr2[j + t];
    uint4 vv[8];
    #pragma unroll
    for (int t = 0; t < 8; ++t) vv[t] = hr[(size_t)rc[t].x * 32 + l];
    #pragma unroll
    for (int t = 0; t < 8; ++t) {
      float s = __int_as_float(rc[t].y) * dc;
      ACC8(vv[t], s);
    }
  }
  for (; j + 3 < je; j += 4) {
    int2 rc0 = csr2[j], rc1 = csr2[j + 1], rc2 = csr2[j + 2], rc3 = csr2[j + 3];
    uint4 v0 = hr[(size_t)rc0.x * 32 + l];
    uint4 v1 = hr[(size_t)rc1.x * 32 + l];
    uint4 v2 = hr[(size_t)rc2.x * 32 + l];
    uint4 v3 = hr[(size_t)rc3.x * 32 + l];
    float s0 = __int_as_float(rc0.y) * dc, s1 = __int_as_float(rc1.y) * dc;
    float s2 = __int_as_float(rc2.y) * dc, s3 = __int_as_float(rc3.y) * dc;
    ACC8(v0, s0); ACC8(v1, s1); ACC8(v2, s2); ACC8(v3, s3);
  }
  for (; j < je; ++j) {
    int2 rc = csr2[j];
    float s = __int_as_float(rc.y) * dc;
    uint4 v = hr[(size_t)rc.x * 32 + l];
    ACC8(v, s);
  }
  #undef ACC8
  float4 b01 = *(const float4*)(bias1 + l * 8);
  float4 b23 = *(const float4*)(bias1 + l * 8 + 4);
  a0 = fmaxf(a0 + b01.x, 0.f); a1 = fmaxf(a1 + b01.y, 0.f);
  a2 = fmaxf(a2 + b01.z, 0.f); a3 = fmaxf(a3 + b01.w, 0.f);
  a4 = fmaxf(a4 + b23.x, 0.f); a5 = fmaxf(a5 + b23.y, 0.f);
  a6 = fmaxf(a6 + b23.z, 0.f); a7 = fmaxf(a7 + b23.w, 0.f);
  uint4 ov;
  ov.x = ((unsigned int)f2bf(a1) << 16) | f2bf(a0);
  ov.y = ((unsigned int)f2bf(a3) << 16) | f2bf(a2);
  ov.z = ((unsigned int)f2bf(a5) << 16) | f2bf(a4);
  ov.w = ((unsigned int)f2bf(a7) << 16) | f2bf(a6);
  ((uint4*)hrelu)[(size_t)c * 32 + l] = ov;
}

// ---------------- GEMM2: bf16 MFMA, [N,256]x[256,64], block tile 128x64 ----------------
__global__ __launch_bounds__(256, 2) void k_gemm2(const unsigned short* __restrict__ A,
                                                  const unsigned short* __restrict__ w2b,
                                                  unsigned short* __restrict__ h3, int N) {
  __shared__ __align__(16) unsigned short B_lds[16384];  // [kc 0..31][n 0..63][ke 0..7]
  __shared__ __align__(16) unsigned short A_lds[8192];   // [kcl 0..7][i 0..127][ke 0..7]
  int tid = threadIdx.x;
  int m0 = blockIdx.x * 128;
  #pragma unroll
  for (int it = 0; it < 8; ++it)
    gload16(((const uint4*)w2b) + it * 256 + tid, &B_lds[((size_t)it * 256 + tid) * 8]);

  int wave = tid >> 6, lane = tid & 63;
  int wr = wave >> 1, wc = wave & 1;
  int hi = lane >> 5, lo = lane & 31;

  f32x16 acc[2];
  #pragma unroll
  for (int mi = 0; mi < 2; ++mi)
    #pragma unroll
    for (int r = 0; r < 16; ++r) acc[mi][r] = 0.f;

  int i = tid & 127;
  int row = m0 + i;
  if (row >= N) row = N - 1;
  const unsigned short* arow = A + (size_t)row * 256;
  int kcl0 = tid >> 7;  // 0..1

  for (int k0 = 0; k0 < 256; k0 += 64) {
    __syncthreads();  // previous compute done (and on first iter, orders vs B issue)
    #pragma unroll
    for (int t = 0; t < 4; ++t)
      gload16(arow + k0 + (kcl0 + 2 * t) * 8,
              &A_lds[((size_t)(kcl0 + 2 * t) * 128 + i) * 8]);
    __syncthreads();  // vmcnt drain: A chunk (and B on first iter) ready
    #pragma unroll
    for (int s = 0; s < 4; ++s) {
      int kcl = s * 2 + hi;
      bf16x8 a0f = *(const bf16x8*)&A_lds[((size_t)kcl * 128 + wr * 64 + lo) * 8];
      bf16x8 a1f = *(const bf16x8*)&A_lds[((size_t)kcl * 128 + wr * 64 + 32 + lo) * 8];
      bf16x8 bf = *(const bf16x8*)&B_lds[(((size_t)(k0 >> 3) + kcl) * 64 + wc * 32 + lo) * 8];
      acc[0] = __builtin_amdgcn_mfma_f32_32x32x16_bf16(a0f, bf, acc[0], 0, 0, 0);
      acc[1] = __builtin_amdgcn_mfma_f32_32x32x16_bf16(a1f, bf, acc[1], 0, 0, 0);
    }
  }

  int n = wc * 32 + lo;
  #pragma unroll
  for (int mi = 0; mi < 2; ++mi) {
    #pragma unroll
    for (int q = 0; q < 4; ++q) {
      #pragma unroll
      for (int j = 0; j < 4; ++j) {
        int r = j + 8 * q + 4 * hi;
        int orow = m0 + wr * 64 + mi * 32 + r;
        if (orow < N) h3[(size_t)orow * 64 + n] = f2bf(acc[mi][q * 4 + j]);
      }
    }
  }
}

// ---------------- propagate 2 (64 feat, bf16): 8 lanes/row, 32 rows/block ----------------
__global__ __launch_bounds__(256) void k_prop2(const unsigned short* __restrict__ h3,
                                               const int* __restrict__ rowptr,
                                               const int2* __restrict__ csr2,
                                               const float* __restrict__ dinv,
                                               const float* __restrict__ bias2,
                                               float* __restrict__ out, int N) {
  int tid = threadIdx.x;
  int c = blockIdx.x * 32 + (tid >> 3);
  int l = tid & 7;                         // 8 features per lane
  if (c >= N) return;
  float dc = dinv[c];
  const uint4* hr = (const uint4*)h3;      // row = 8 uint4
  uint4 sv = hr[(size_t)c * 8 + l];
  float slf = dc * dc;
  float a0, a1, a2, a3, a4, a5, a6, a7;
  {
    float lo, hi;
    bf2x(sv.x, lo, hi); a0 = lo * slf; a1 = hi * slf;
    bf2x(sv.y, lo, hi); a2 = lo * slf; a3 = hi * slf;
    bf2x(sv.z, lo, hi); a4 = lo * slf; a5 = hi * slf;
    bf2x(sv.w, lo, hi); a6 = lo * slf; a7 = hi * slf;
  }
  int jb = rowptr[c], je = rowptr[c + 1];
  int j = jb;
  #define ACC8(v, s) { float lo, hi; \
    bf2x((v).x, lo, hi); a0 += lo * (s); a1 += hi * (s); \
    bf2x((v).y, lo, hi); a2 += lo * (s); a3 += hi * (s); \
    bf2x((v).z, lo, hi); a4 += lo * (s); a5 += hi * (s); \
    bf2x((v).w, lo, hi); a6 += lo * (s); a7 += hi * (s); }
  for (; j + 7 < je; j += 8) {
    int2 rc[8];
    #pragma unroll
    for (int t = 0; t < 8; ++t) rc[t] = csr2[j + t];
    uint4 vv[8];
    #pragma unroll
    for (int t = 0; t < 8; ++t) vv[t] = hr[(size_t)rc[t].x * 8 + l];
    #pragma unroll
    for (int t = 0; t < 8; ++t) {
      float s = __int_as_float(rc[t].y) * dc;
      ACC8(vv[t], s);
    }
  }
  for (; j + 3 < je; j += 4) {
    int2 rc0 = csr2[j], rc1 = csr2[j + 1], rc2 = csr2[j + 2], rc3 = csr2[j + 3];
    uint4 v0 = hr[(size_t)rc0.x * 8 + l];
    uint4 v1 = hr[(size_t)rc1.x * 8 + l];
    uint4 v2 = hr[(size_t)rc2.x * 8 + l];
    uint4 v3 = hr[(size_t)rc3.x * 8 + l];
    float s0 = __int_as_float(rc0.y) * dc, s1 = __int_as_float(rc1.y) * dc;
    float s2 = __int_as_float(rc2.y) * dc, s3 = __int_as_float(rc3.y) * dc;
    ACC8(v0, s0); ACC8(v1, s1); ACC8(v2, s2); ACC8(v3, s3);
  }
  for (; j < je; ++j) {
    int2 rc = csr2[j];
    float s = __int_as_float(rc.y) * dc;
    uint4 v = hr[(size_t)rc.x * 8 + l];
    ACC8(v, s);
  }
  #undef ACC8
  float4 b01 = *(const float4*)(bias2 + l * 8);
  float4 b23 = *(const float4*)(bias2 + l * 8 + 4);
  a0 += b01.x; a1 += b01.y; a2 += b01.z; a3 += b01.w;
  a4 += b23.x; a5 += b23.y; a6 += b23.z; a7 += b23.w;
  // log_softmax over 64 features spread across 8 lanes x 8 values
  float m = fmaxf(fmaxf(fmaxf(a0, a1), fmaxf(a2, a3)), fmaxf(fmaxf(a4, a5), fmaxf(a6, a7)));
  #pragma unroll
  for (int off = 4; off > 0; off >>= 1) m = fmaxf(m, __shfl_xor(m, off, 64));
  float s = expf(a0 - m) + expf(a1 - m) + expf(a2 - m) + expf(a3 - m)
          + expf(a4 - m) + expf(a5 - m) + expf(a6 - m) + expf(a7 - m);
  #pragma unroll
  for (int off = 4; off > 0; off >>= 1) s += __shfl_xor(s, off, 64);
  float ls = m + logf(s);
  float* orow = out + (size_t)c * 64 + l * 8;
  float4 o0 = make_float4(a0 - ls, a1 - ls, a2 - ls, a3 - ls);
  float4 o1 = make_float4(a4 - ls, a5 - ls, a6 - ls, a7 - ls);
  *(float4*)orow = o0;
  *(float4*)(orow + 4) = o1;
}

// ---------------- launch ----------------
extern "C" void kernel_launch(void* const* d_in, const int* in_sizes, int n_in,
                              void* d_out, int out_size, void* d_ws, size_t ws_size,
                              hipStream_t stream) {
  const float* x  = (const float*)d_in[0];
  const int*   ei = (const int*)d_in[1];
  const float* wg = (const float*)d_in[2];
  const float* ew = (const float*)d_in[3];
  const float* eb = (const float*)d_in[4];
  const float* b1 = (const float*)d_in[5];
  const float* w2 = (const float*)d_in[6];
  const float* b2 = (const float*)d_in[7];
  float* out = (float*)d_out;

  int N = in_sizes[0] / 512;
  int E = in_sizes[1] / 2;
  const int* row = ei;
  const int* col = ei + E;

  char* p = (char*)d_ws;
  auto alloc = [&](size_t bytes) -> void* {
    void* r = (void*)p;
    p += (bytes + 255) & ~(size_t)255;
    return r;
  };
  int*   cnt    = (int*)alloc((size_t)N * 4);
  int*   rowptr = (int*)alloc((size_t)(N + 1) * 4);
  int*   cursor = (int*)alloc((size_t)N * 4);
  int*   bsums  = (int*)alloc(1024 * 4);
  int*   boff   = (int*)alloc(1024 * 4);
  float* dinv   = (float*)alloc((size_t)N * 4);
  int*   eidx   = (int*)alloc((size_t)N * 4);
  int*   meta   = (int*)alloc(32 * 4);
  int*   perm   = (int*)alloc((size_t)N * 4);
  int2*  csr2   = (int2*)alloc((size_t)E * 8);
  unsigned short* h1    = (unsigned short*)alloc((size_t)N * 256 * 2);
  unsigned short* hrelu = (unsigned short*)alloc((size_t)N * 256 * 2);
  unsigned short* h3    = (unsigned short*)alloc((size_t)N * 64 * 2);
  unsigned short* xb  = (unsigned short*)alloc((size_t)N * 512 * 2);
  unsigned short* ewb = (unsigned short*)alloc((size_t)4 * 512 * 256 * 2);
  unsigned short* w2b = (unsigned short*)alloc((size_t)256 * 64 * 2);

  int nb = (N + 1023) / 1024;
  int gateB = (N + 15) / 16;
  int cntB = (E + 255) / 256;
  int scatB = (E + 255) / 256;
  int binB = (N + 255) / 256;

  k_init<<<(N + 255) / 256, 256, 0, stream>>>(cnt, meta, N);
  // fused + interleaved: gate (+x cast) | degree count | weight pack
  k_gate<<<gateB + cntB + 288, 256, 0, stream>>>(x, wg, eidx, meta, xb, col, cnt,
                                                 ew, ewb, w2, w2b, N, E, gateB, cntB);
  k_scanA<<<nb, 256, 0, stream>>>(cnt, rowptr, bsums, N);
  k_scanB<<<1, 256, 0, stream>>>(bsums, boff, nb);
  k_scanC<<<(N + 255) / 256, 256, 0, stream>>>(cnt, rowptr, boff, rowptr, cursor, dinv,
                                               meta, N, E);
  // fused: edge scatter | expert binscatter
  k_scatter<<<scatB + binB, 256, 0, stream>>>(row, col, cursor, dinv, csr2, E,
                                              eidx, meta, perm, N, scatB);
  int ntiles = (N + 127) / 128 + 4;
  k_gemm1<<<ntiles, 512, 0, stream>>>(xb, ewb, eb, perm, meta, h1);
  k_prop1<<<(N + 7) / 8, 256, 0, stream>>>(h1, rowptr, csr2, dinv, b1, hrelu, N);
  k_gemm2<<<(N + 127) / 128, 256, 0, stream>>>(hrelu, w2b, h3, N);
  k_prop2<<<(N + 31) / 32, 256, 0, stream>>>(h3, rowptr, csr2, dinv, b2, out, N);
}

// Round 13
// 351.975 us; speedup vs baseline: 1.0085x; 1.0085x over previous
//
#include <hip/hip_runtime.h>
#include <math.h>

typedef __bf16 bf16x8 __attribute__((ext_vector_type(8)));
typedef float f32x16 __attribute__((ext_vector_type(16)));

// ---------------- helpers ----------------
__device__ __forceinline__ unsigned short f2bf(float f) {
  union { float f; unsigned int u; } v; v.f = f;
  unsigned int r = (v.u + 0x7FFFu + ((v.u >> 16) & 1u)) >> 16;
  return (unsigned short)r;
}
__device__ __forceinline__ float bf2f(unsigned short u) {
  union { unsigned int u; float f; } v; v.u = ((unsigned int)u) << 16;
  return v.f;
}
// unpack 2 bf16 from one u32 (memory order: low half = even element)
__device__ __forceinline__ void bf2x(unsigned int u, float& lo, float& hi) {
  union { unsigned int u; float f; } a, b;
  a.u = u << 16; b.u = u & 0xFFFF0000u;
  lo = a.f; hi = b.f;
}
// async global->LDS 16B copy (global_load_lds_dwordx4)
__device__ __forceinline__ void gload16(const void* g, void* l) {
  __builtin_amdgcn_global_load_lds(
      (__attribute__((address_space(1))) void*)const_cast<void*>(g),
      (__attribute__((address_space(3))) void*)l, 16, 0, 0);
}

// ---------------- setup kernels ----------------
__global__ void k_init(int* cnt, int* meta, int N) {
  int i = blockIdx.x * blockDim.x + threadIdx.x;
  if (i < N) cnt[i] = 0;
  if (i < 32) meta[i] = 0;
}

__global__ __launch_bounds__(256) void k_scanA(const int* __restrict__ cnt,
                                               int* __restrict__ incl,
                                               int* __restrict__ bsums, int N) {
  __shared__ int s[1024];
  int base = blockIdx.x * 1024;
  #pragma unroll
  for (int t = 0; t < 4; ++t) {
    int i = threadIdx.x + t * 256;
    int idx = base + i;
    s[i] = (idx < N) ? cnt[idx] : 0;
  }
  __syncthreads();
  for (int d = 1; d < 1024; d <<= 1) {
    int v[4];
    #pragma unroll
    for (int t = 0; t < 4; ++t) {
      int i = threadIdx.x + t * 256;
      v[t] = (i >= d) ? s[i - d] : 0;
    }
    __syncthreads();
    #pragma unroll
    for (int t = 0; t < 4; ++t) {
      int i = threadIdx.x + t * 256;
      s[i] += v[t];
    }
    __syncthreads();
  }
  #pragma unroll
  for (int t = 0; t < 4; ++t) {
    int i = threadIdx.x + t * 256;
    int idx = base + i;
    if (idx < N) incl[idx] = s[i];
  }
  if (threadIdx.x == 0) bsums[blockIdx.x] = s[1023];
}

__global__ __launch_bounds__(256) void k_scanB(const int* __restrict__ bsums,
                                               int* __restrict__ boff, int nb) {
  __shared__ int s[1024];
  #pragma unroll
  for (int t = 0; t < 4; ++t) {
    int i = threadIdx.x + t * 256;
    s[i] = (i < nb) ? bsums[i] : 0;
  }
  __syncthreads();
  for (int d = 1; d < 1024; d <<= 1) {
    int v[4];
    #pragma unroll
    for (int t = 0; t < 4; ++t) {
      int i = threadIdx.x + t * 256;
      v[t] = (i >= d) ? s[i - d] : 0;
    }
    __syncthreads();
    #pragma unroll
    for (int t = 0; t < 4; ++t) {
      int i = threadIdx.x + t * 256;
      s[i] += v[t];
    }
    __syncthreads();
  }
  #pragma unroll
  for (int t = 0; t < 4; ++t) {
    int i = threadIdx.x + t * 256;
    if (i < nb) boff[i] = (i == 0) ? 0 : s[i - 1];
  }
}

// scanC + fused offs (meta hist is final: gate kernel completed before scanA)
__global__ void k_scanC(const int* __restrict__ cnt, const int* __restrict__ incl,
                        const int* __restrict__ boff, int* __restrict__ rowptr,
                        int* __restrict__ cursor, float* __restrict__ dinv,
                        int* __restrict__ meta, int N, int E) {
  int i = blockIdx.x * blockDim.x + threadIdx.x;
  if (i < N) {
    int ex = incl[i] - cnt[i] + boff[i >> 10];
    rowptr[i] = ex;
    cursor[i] = ex;
    dinv[i] = rsqrtf((float)(cnt[i] + 1));
    if (i == 0) rowptr[N] = E;
  }
  if (blockIdx.x == 0 && threadIdx.x == 0) {
    int* hist = meta;
    int* eoff = meta + 4;
    int* toff = meta + 9;
    int* ecur = meta + 14;
    int s = 0, t = 0;
    eoff[0] = 0; toff[0] = 0;
    for (int e = 0; e < 4; ++e) {
      s += hist[e];
      eoff[e + 1] = s;
      t += (hist[e] + 127) / 128;
      toff[e + 1] = t;
      ecur[e] = eoff[e];
    }
  }
}

// scatter edge -> csr2 {row, dinv[row]}; appended blocks do binscatter
__global__ __launch_bounds__(256) void k_scatter(const int* __restrict__ row,
                                                 const int* __restrict__ col,
                                                 int* __restrict__ cursor,
                                                 const float* __restrict__ dinv,
                                                 int2* __restrict__ csr2, int E,
                                                 const int* __restrict__ eidx,
                                                 int* __restrict__ meta,
                                                 int* __restrict__ perm, int N, int scatB) {
  int tid = threadIdx.x;
  if (blockIdx.x < (unsigned)scatB) {
    int e = blockIdx.x * 256 + tid;
    if (e < E) {
      int c = col[e];
      int r = row[e];
      int p = atomicAdd(&cursor[c], 1);
      csr2[p] = make_int2(r, __float_as_int(dinv[r]));
    }
    return;
  }
  // ---- binscatter (needs offs: done in k_scanC, prior launch) ----
  __shared__ int lhist[4];
  __shared__ int lbase[4];
  if (tid < 4) lhist[tid] = 0;
  __syncthreads();
  int n = (blockIdx.x - scatB) * 256 + tid;
  int e = 0, lrank = 0;
  bool valid = (n < N);
  if (valid) {
    e = eidx[n];
    lrank = atomicAdd(&lhist[e], 1);
  }
  __syncthreads();
  if (tid < 4) {
    int c = lhist[tid];
    lbase[tid] = (c > 0) ? atomicAdd(&meta[14 + tid], c) : 0;
  }
  __syncthreads();
  if (valid) perm[lbase[e] + lrank] = n;
}

// ---------------- fused gate (+bf16 cast of x) / degree-count / weight-pack ----------------
// Roles INTERLEAVED across the grid so count's atomic latency overlaps gate's streaming:
// within [0, 3*usedC): b%3==2 -> count(b/3), else gate(2*(b/3)+b%3); leftovers appended; pack last.
__global__ __launch_bounds__(256) void k_gate(const float* __restrict__ x,
                                              const float* __restrict__ wg,
                                              int* __restrict__ eidx,
                                              int* __restrict__ meta,
                                              unsigned short* __restrict__ xb,
                                              const int* __restrict__ col,
                                              int* __restrict__ cnt,
                                              const float* __restrict__ ew,
                                              unsigned short* __restrict__ ewb,
                                              const float* __restrict__ w2,
                                              unsigned short* __restrict__ w2b,
                                              int N, int E, int gateB, int cntB) {
  int tid = threadIdx.x;
  int b = blockIdx.x;
  int usedC = min(cntB, gateB / 2);
  int mix3 = 3 * usedC;
  int role, idx;                     // 0=gate 1=count 2=pack
  if (b < mix3) {
    if ((b % 3) == 2) { role = 1; idx = b / 3; }
    else              { role = 0; idx = (b / 3) * 2 + (b % 3); }
  } else {
    int r = b - mix3;
    int gLeft = gateB - 2 * usedC;
    if (r < gLeft) { role = 0; idx = 2 * usedC + r; }
    else {
      r -= gLeft;
      int cLeft = cntB - usedC;
      if (r < cLeft) { role = 1; idx = usedC + r; }
      else           { role = 2; idx = r - cLeft; }
    }
  }

  if (role == 1) {                   // ---- degree count ----
    int e = idx * 256 + tid;
    if (e < E) atomicAdd(&cnt[col[e]], 1);
    return;
  }
  if (role == 2) {                   // ---- weight pack ----
    if (idx < 256) {                 // ew: idx = e*64 + kc
      int n = tid;
      int eidx2 = idx >> 6, kc = idx & 63;
      const float* src = ew + ((size_t)eidx2 * 512 + (size_t)kc * 8) * 256 + n;
      unsigned short tmp[8];
      #pragma unroll
      for (int ke = 0; ke < 8; ++ke) tmp[ke] = f2bf(src[(size_t)ke * 256]);
      *(uint4*)(ewb + ((size_t)idx * 256 + n) * 8) = *(const uint4*)tmp;
    } else {                         // w2: kc = idx-256 in 0..31
      int kc = idx - 256;
      if (tid < 64) {
        const float* src = w2 + (size_t)kc * 8 * 64 + tid;
        unsigned short tmp[8];
        #pragma unroll
        for (int ke = 0; ke < 8; ++ke) tmp[ke] = f2bf(src[(size_t)ke * 64]);
        *(uint4*)(w2b + ((size_t)kc * 64 + tid) * 8) = *(const uint4*)tmp;
      }
    }
    return;
  }

  // ---- gating: wg transposed in LDS; 8 independent x loads up front ----
  __shared__ float wgT[4][512];
  __shared__ int lhist[4];
  if (tid < 4) lhist[tid] = 0;
  {
    int r0 = tid * 2;
    float4 wa = *(const float4*)(wg + 4 * r0);
    float4 wb = *(const float4*)(wg + 4 * (r0 + 1));
    wgT[0][r0] = wa.x; wgT[1][r0] = wa.y; wgT[2][r0] = wa.z; wgT[3][r0] = wa.w;
    wgT[0][r0 + 1] = wb.x; wgT[1][r0 + 1] = wb.y; wgT[2][r0 + 1] = wb.z; wgT[3][r0 + 1] = wb.w;
  }
  __syncthreads();
  int node = idx * 16 + (tid >> 4);
  int sl = tid & 15;
  if (node < N) {
    const float* xr = x + (size_t)node * 512;
    unsigned short* xbr = xb + (size_t)node * 512;
    float4 xv[8];
    #pragma unroll
    for (int j = 0; j < 8; ++j) xv[j] = *(const float4*)(xr + 4 * (sl + 16 * j));
    #pragma unroll
    for (int j = 0; j < 8; ++j) {
      ushort4 ov;
      ov.x = f2bf(xv[j].x); ov.y = f2bf(xv[j].y); ov.z = f2bf(xv[j].z); ov.w = f2bf(xv[j].w);
      *(ushort4*)(xbr + 4 * (sl + 16 * j)) = ov;
    }
    float l0 = 0.f, l1 = 0.f, l2 = 0.f, l3 = 0.f;
    #pragma unroll
    for (int j = 0; j < 8; ++j) {
      int k0 = 4 * (sl + 16 * j);
      float4 w0 = *(const float4*)&wgT[0][k0];
      float4 w1 = *(const float4*)&wgT[1][k0];
      float4 w2v = *(const float4*)&wgT[2][k0];
      float4 w3 = *(const float4*)&wgT[3][k0];
      l0 += xv[j].x * w0.x + xv[j].y * w0.y + xv[j].z * w0.z + xv[j].w * w0.w;
      l1 += xv[j].x * w1.x + xv[j].y * w1.y + xv[j].z * w1.z + xv[j].w * w1.w;
      l2 += xv[j].x * w2v.x + xv[j].y * w2v.y + xv[j].z * w2v.z + xv[j].w * w2v.w;
      l3 += xv[j].x * w3.x + xv[j].y * w3.y + xv[j].z * w3.z + xv[j].w * w3.w;
    }
    #pragma unroll
    for (int off = 8; off > 0; off >>= 1) {
      l0 += __shfl_xor(l0, off, 64);
      l1 += __shfl_xor(l1, off, 64);
      l2 += __shfl_xor(l2, off, 64);
      l3 += __shfl_xor(l3, off, 64);
    }
    if (sl == 0) {
      int a = 0; float best = l0;
      if (l1 > best) { best = l1; a = 1; }
      if (l2 > best) { best = l2; a = 2; }
      if (l3 > best) { best = l3; a = 3; }
      eidx[node] = a;
      atomicAdd(&lhist[a], 1);
    }
  }
  __syncthreads();
  if (tid < 4 && lhist[tid] > 0) atomicAdd(&meta[tid], lhist[tid]);
}

// ---------------- expert GEMM: bf16 MFMA 32x32x16, block tile 128x256 ----------------
__global__ __launch_bounds__(512, 2) void k_gemm1(const unsigned short* __restrict__ xb,
                                                  const unsigned short* __restrict__ ewb,
                                                  const float* __restrict__ eb,
                                                  const int* __restrict__ perm,
                                                  const int* __restrict__ meta,
                                                  unsigned short* __restrict__ h1) {
  __shared__ __align__(16) unsigned short A_lds[8192];    // [kcl 0..7][i 0..127][ke 0..7]
  __shared__ __align__(16) unsigned short B_lds[16384];   // [kcl 0..7][n 0..255][ke 0..7]
  __shared__ int sperm[128];
  const int* eoff = meta + 4;
  const int* toff = meta + 9;
  int v = blockIdx.x;
  if (v >= toff[4]) return;
  int e = 0;
  while (v >= toff[e + 1]) ++e;
  int m0 = eoff[e] + (v - toff[e]) * 128;
  int mEnd = eoff[e + 1];
  int tid = threadIdx.x;

  if (tid < 128) {
    int m = m0 + tid;
    sperm[tid] = perm[(m < mEnd) ? m : (mEnd - 1)];
  }
  __syncthreads();

  int wave = tid >> 6, lane = tid & 63;
  int wr = wave >> 2, wc = wave & 3;
  int hi = lane >> 5, lo = lane & 31;
  int r128 = tid & 127;

  f32x16 acc[2][2];
  #pragma unroll
  for (int mi = 0; mi < 2; ++mi)
    #pragma unroll
    for (int ni = 0; ni < 2; ++ni)
      #pragma unroll
      for (int r = 0; r < 16; ++r) acc[mi][ni][r] = 0.f;

  const unsigned short* arow = xb + (size_t)sperm[r128] * 512;
  int kclA = tid >> 7;  // 0..3
  const uint4* ebase = (const uint4*)(ewb + (size_t)e * 64 * 2048);

  for (int k0 = 0; k0 < 512; k0 += 64) {
    __syncthreads();  // previous chunk's compute done before LDS overwrite
    gload16(arow + k0 + kclA * 8,       &A_lds[((size_t)kclA * 128 + r128) * 8]);
    gload16(arow + k0 + (kclA + 4) * 8, &A_lds[((size_t)(kclA + 4) * 128 + r128) * 8]);
    const uint4* bsrc = ebase + (size_t)(k0 >> 3) * 256;
    gload16(bsrc + tid,        &B_lds[((size_t)0 * 512 + tid) * 8]);
    gload16(bsrc + 512 + tid,  &B_lds[((size_t)1 * 512 + tid) * 8]);
    gload16(bsrc + 1024 + tid, &B_lds[((size_t)2 * 512 + tid) * 8]);
    gload16(bsrc + 1536 + tid, &B_lds[((size_t)3 * 512 + tid) * 8]);
    __syncthreads();  // vmcnt(0) drain -> LDS ready
    #pragma unroll
    for (int s = 0; s < 4; ++s) {
      int kcl = s * 2 + hi;
      bf16x8 a0f = *(const bf16x8*)&A_lds[((size_t)kcl * 128 + wr * 64 + lo) * 8];
      bf16x8 a1f = *(const bf16x8*)&A_lds[((size_t)kcl * 128 + wr * 64 + 32 + lo) * 8];
      bf16x8 b0f = *(const bf16x8*)&B_lds[((size_t)kcl * 256 + wc * 64 + lo) * 8];
      bf16x8 b1f = *(const bf16x8*)&B_lds[((size_t)kcl * 256 + wc * 64 + 32 + lo) * 8];
      acc[0][0] = __builtin_amdgcn_mfma_f32_32x32x16_bf16(a0f, b0f, acc[0][0], 0, 0, 0);
      acc[0][1] = __builtin_amdgcn_mfma_f32_32x32x16_bf16(a0f, b1f, acc[0][1], 0, 0, 0);
      acc[1][0] = __builtin_amdgcn_mfma_f32_32x32x16_bf16(a1f, b0f, acc[1][0], 0, 0, 0);
      acc[1][1] = __builtin_amdgcn_mfma_f32_32x32x16_bf16(a1f, b1f, acc[1][1], 0, 0, 0);
    }
  }

  // epilogue: bias + scatter rows as bf16. C/D: col=lane&31, row=(reg&3)+8*(reg>>2)+4*(lane>>5)
  #pragma unroll
  for (int ni = 0; ni < 2; ++ni) {
    int col = wc * 64 + ni * 32 + lo;
    float bias = eb[e * 256 + col];
    #pragma unroll
    for (int mi = 0; mi < 2; ++mi) {
      #pragma unroll
      for (int q = 0; q < 4; ++q) {
        #pragma unroll
        for (int j = 0; j < 4; ++j) {
          int r = j + 8 * q + 4 * hi;
          int lrow = wr * 64 + mi * 32 + r;
          if (m0 + lrow < mEnd) {
            h1[(size_t)sperm[lrow] * 256 + col] = f2bf(acc[mi][ni][q * 4 + j] + bias);
          }
        }
      }
    }
  }
}

// ---------------- propagate 1 (256 feat, bf16): 32 lanes/row, 8 rows/block ----------------
__global__ __launch_bounds__(256) void k_prop1(const unsigned short* __restrict__ h1,
                                               const int* __restrict__ rowptr,
                                               const int2* __restrict__ csr2,
                                               const float* __restrict__ dinv,
                                               const float* __restrict__ bias1,
                                               unsigned short* __restrict__ hrelu, int N) {
  int tid = threadIdx.x;
  int c = blockIdx.x * 8 + (tid >> 5);
  int l = tid & 31;                        // 8 features per lane
  if (c >= N) return;
  float dc = dinv[c];
  const uint4* hr = (const uint4*)h1;      // row = 32 uint4
  uint4 sv = hr[(size_t)c * 32 + l];
  float slf = dc * dc;
  float a0, a1, a2, a3, a4, a5, a6, a7;
  {
    float lo, hi;
    bf2x(sv.x, lo, hi); a0 = lo * slf; a1 = hi * slf;
    bf2x(sv.y, lo, hi); a2 = lo * slf; a3 = hi * slf;
    bf2x(sv.z, lo, hi); a4 = lo * slf; a5 = hi * slf;
    bf2x(sv.w, lo, hi); a6 = lo * slf; a7 = hi * slf;
  }
  int jb = rowptr[c], je = rowptr[c + 1];
  int j = jb;
  #define ACC8(v, s) { float lo, hi; \
    bf2x((v).x, lo, hi); a0 += lo * (s); a1 += hi * (s); \
    bf2x((v).y, lo, hi); a2 += lo * (s); a3 += hi * (s); \
    bf2x((v).z, lo, hi); a4 += lo * (s); a5 += hi * (s); \
    bf2x((v).w, lo, hi); a6 += lo * (s); a7 += hi * (s); }
  for (; j + 7 < je; j += 8) {
    int2 rc[8];
    #pragma unroll
    for (int t = 0; t < 8; ++t) rc[t] = csr2[j + t];
    uint4 vv[8];
    #pragma unroll
    for (int t = 0; t < 8; ++t) vv[t] = hr[(size_t)rc[t].x * 32 + l];
    #pragma unroll
    for (int t = 0; t < 8; ++t) {
      float s = __int_as_float(rc[t].y) * dc;
      ACC8(vv[t], s);
    }
  }
  for (; j + 3 < je; j += 4) {
    int2 rc0 = csr2[j], rc1 = csr2[j + 1], rc2 = csr2[j + 2], rc3 = csr2[j + 3];
    uint4 v0 = hr[(size_t)rc0.x * 32 + l];
    uint4 v1 = hr[(size_t)rc1.x * 32 + l];
    uint4 v2 = hr[(size_t)rc2.x * 32 + l];
    uint4 v3 = hr[(size_t)rc3.x * 32 + l];
    float s0 = __int_as_float(rc0.y) * dc, s1 = __int_as_float(rc1.y) * dc;
    float s2 = __int_as_float(rc2.y) * dc, s3 = __int_as_float(rc3.y) * dc;
    ACC8(v0, s0); ACC8(v1, s1); ACC8(v2, s2); ACC8(v3, s3);
  }
  for (; j < je; ++j) {
    int2 rc = csr2[j];
    float s = __int_as_float(rc.y) * dc;
    uint4 v = hr[(size_t)rc.x * 32 + l];
    ACC8(v, s);
  }
  #undef ACC8
  float4 b01 = *(const float4*)(bias1 + l * 8);
  float4 b23 = *(const float4*)(bias1 + l * 8 + 4);
  a0 = fmaxf(a0 + b01.x, 0.f); a1 = fmaxf(a1 + b01.y, 0.f);
  a2 = fmaxf(a2 + b01.z, 0.f); a3 = fmaxf(a3 + b01.w, 0.f);
  a4 = fmaxf(a4 + b23.x, 0.f); a5 = fmaxf(a5 + b23.y, 0.f);
  a6 = fmaxf(a6 + b23.z, 0.f); a7 = fmaxf(a7 + b23.w, 0.f);
  uint4 ov;
  ov.x = ((unsigned int)f2bf(a1) << 16) | f2bf(a0);
  ov.y = ((unsigned int)f2bf(a3) << 16) | f2bf(a2);
  ov.z = ((unsigned int)f2bf(a5) << 16) | f2bf(a4);
  ov.w = ((unsigned int)f2bf(a7) << 16) | f2bf(a6);
  ((uint4*)hrelu)[(size_t)c * 32 + l] = ov;
}

// ---------------- GEMM2: bf16 MFMA, [N,256]x[256,64], block tile 128x64 ----------------
__global__ __launch_bounds__(256, 2) void k_gemm2(const unsigned short* __restrict__ A,
                                                  const unsigned short* __restrict__ w2b,
                                                  unsigned short* __restrict__ h3, int N) {
  __shared__ __align__(16) unsigned short B_lds[16384];  // [kc 0..31][n 0..63][ke 0..7]
  __shared__ __align__(16) unsigned short A_lds[8192];   // [kcl 0..7][i 0..127][ke 0..7]
  int tid = threadIdx.x;
  int m0 = blockIdx.x * 128;
  #pragma unroll
  for (int it = 0; it < 8; ++it)
    gload16(((const uint4*)w2b) + it * 256 + tid, &B_lds[((size_t)it * 256 + tid) * 8]);

  int wave = tid >> 6, lane = tid & 63;
  int wr = wave >> 1, wc = wave & 1;
  int hi = lane >> 5, lo = lane & 31;

  f32x16 acc[2];
  #pragma unroll
  for (int mi = 0; mi < 2; ++mi)
    #pragma unroll
    for (int r = 0; r < 16; ++r) acc[mi][r] = 0.f;

  int i = tid & 127;
  int row = m0 + i;
  if (row >= N) row = N - 1;
  const unsigned short* arow = A + (size_t)row * 256;
  int kcl0 = tid >> 7;  // 0..1

  for (int k0 = 0; k0 < 256; k0 += 64) {
    __syncthreads();  // previous compute done (and on first iter, orders vs B issue)
    #pragma unroll
    for (int t = 0; t < 4; ++t)
      gload16(arow + k0 + (kcl0 + 2 * t) * 8,
              &A_lds[((size_t)(kcl0 + 2 * t) * 128 + i) * 8]);
    __syncthreads();  // vmcnt drain: A chunk (and B on first iter) ready
    #pragma unroll
    for (int s = 0; s < 4; ++s) {
      int kcl = s * 2 + hi;
      bf16x8 a0f = *(const bf16x8*)&A_lds[((size_t)kcl * 128 + wr * 64 + lo) * 8];
      bf16x8 a1f = *(const bf16x8*)&A_lds[((size_t)kcl * 128 + wr * 64 + 32 + lo) * 8];
      bf16x8 bf = *(const bf16x8*)&B_lds[(((size_t)(k0 >> 3) + kcl) * 64 + wc * 32 + lo) * 8];
      acc[0] = __builtin_amdgcn_mfma_f32_32x32x16_bf16(a0f, bf, acc[0], 0, 0, 0);
      acc[1] = __builtin_amdgcn_mfma_f32_32x32x16_bf16(a1f, bf, acc[1], 0, 0, 0);
    }
  }

  int n = wc * 32 + lo;
  #pragma unroll
  for (int mi = 0; mi < 2; ++mi) {
    #pragma unroll
    for (int q = 0; q < 4; ++q) {
      #pragma unroll
      for (int j = 0; j < 4; ++j) {
        int r = j + 8 * q + 4 * hi;
        int orow = m0 + wr * 64 + mi * 32 + r;
        if (orow < N) h3[(size_t)orow * 64 + n] = f2bf(acc[mi][q * 4 + j]);
      }
    }
  }
}

// ---------------- propagate 2 (64 feat, bf16): 8 lanes/row, 32 rows/block ----------------
__global__ __launch_bounds__(256) void k_prop2(const unsigned short* __restrict__ h3,
                                               const int* __restrict__ rowptr,
                                               const int2* __restrict__ csr2,
                                               const float* __restrict__ dinv,
                                               const float* __restrict__ bias2,
                                               float* __restrict__ out, int N) {
  int tid = threadIdx.x;
  int c = blockIdx.x * 32 + (tid >> 3);
  int l = tid & 7;                         // 8 features per lane
  if (c >= N) return;
  float dc = dinv[c];
  const uint4* hr = (const uint4*)h3;      // row = 8 uint4
  uint4 sv = hr[(size_t)c * 8 + l];
  float slf = dc * dc;
  float a0, a1, a2, a3, a4, a5, a6, a7;
  {
    float lo, hi;
    bf2x(sv.x, lo, hi); a0 = lo * slf; a1 = hi * slf;
    bf2x(sv.y, lo, hi); a2 = lo * slf; a3 = hi * slf;
    bf2x(sv.z, lo, hi); a4 = lo * slf; a5 = hi * slf;
    bf2x(sv.w, lo, hi); a6 = lo * slf; a7 = hi * slf;
  }
  int jb = rowptr[c], je = rowptr[c + 1];
  int j = jb;
  #define ACC8(v, s) { float lo, hi; \
    bf2x((v).x, lo, hi); a0 += lo * (s); a1 += hi * (s); \
    bf2x((v).y, lo, hi); a2 += lo * (s); a3 += hi * (s); \
    bf2x((v).z, lo, hi); a4 += lo * (s); a5 += hi * (s); \
    bf2x((v).w, lo, hi); a6 += lo * (s); a7 += hi * (s); }
  for (; j + 7 < je; j += 8) {
    int2 rc[8];
    #pragma unroll
    for (int t = 0; t < 8; ++t) rc[t] = csr2[j + t];
    uint4 vv[8];
    #pragma unroll
    for (int t = 0; t < 8; ++t) vv[t] = hr[(size_t)rc[t].x * 8 + l];
    #pragma unroll
    for (int t = 0; t < 8; ++t) {
      float s = __int_as_float(rc[t].y) * dc;
      ACC8(vv[t], s);
    }
  }
  for (; j + 3 < je; j += 4) {
    int2 rc0 = csr2[j], rc1 = csr2[j + 1], rc2 = csr2[j + 2], rc3 = csr2[j + 3];
    uint4 v0 = hr[(size_t)rc0.x * 8 + l];
    uint4 v1 = hr[(size_t)rc1.x * 8 + l];
    uint4 v2 = hr[(size_t)rc2.x * 8 + l];
    uint4 v3 = hr[(size_t)rc3.x * 8 + l];
    float s0 = __int_as_float(rc0.y) * dc, s1 = __int_as_float(rc1.y) * dc;
    float s2 = __int_as_float(rc2.y) * dc, s3 = __int_as_float(rc3.y) * dc;
    ACC8(v0, s0); ACC8(v1, s1); ACC8(v2, s2); ACC8(v3, s3);
  }
  for (; j < je; ++j) {
    int2 rc = csr2[j];
    float s = __int_as_float(rc.y) * dc;
    uint4 v = hr[(size_t)rc.x * 8 + l];
    ACC8(v, s);
  }
  #undef ACC8
  float4 b01 = *(const float4*)(bias2 + l * 8);
  float4 b23 = *(const float4*)(bias2 + l * 8 + 4);
  a0 += b01.x; a1 += b01.y; a2 += b01.z; a3 += b01.w;
  a4 += b23.x; a5 += b23.y; a6 += b23.z; a7 += b23.w;
  // log_softmax over 64 features spread across 8 lanes x 8 values
  float m = fmaxf(fmaxf(fmaxf(a0, a1), fmaxf(a2, a3)), fmaxf(fmaxf(a4, a5), fmaxf(a6, a7)));
  #pragma unroll
  for (int off = 4; off > 0; off >>= 1) m = fmaxf(m, __shfl_xor(m, off, 64));
  float s = expf(a0 - m) + expf(a1 - m) + expf(a2 - m) + expf(a3 - m)
          + expf(a4 - m) + expf(a5 - m) + expf(a6 - m) + expf(a7 - m);
  #pragma unroll
  for (int off = 4; off > 0; off >>= 1) s += __shfl_xor(s, off, 64);
  float ls = m + logf(s);
  float* orow = out + (size_t)c * 64 + l * 8;
  float4 o0 = make_float4(a0 - ls, a1 - ls, a2 - ls, a3 - ls);
  float4 o1 = make_float4(a4 - ls, a5 - ls, a6 - ls, a7 - ls);
  *(float4*)orow = o0;
  *(float4*)(orow + 4) = o1;
}

// ---------------- launch ----------------
extern "C" void kernel_launch(void* const* d_in, const int* in_sizes, int n_in,
                              void* d_out, int out_size, void* d_ws, size_t ws_size,
                              hipStream_t stream) {
  const float* x  = (const float*)d_in[0];
  const int*   ei = (const int*)d_in[1];
  const float* wg = (const float*)d_in[2];
  const float* ew = (const float*)d_in[3];
  const float* eb = (const float*)d_in[4];
  const float* b1 = (const float*)d_in[5];
  const float* w2 = (const float*)d_in[6];
  const float* b2 = (const float*)d_in[7];
  float* out = (float*)d_out;

  int N = in_sizes[0] / 512;
  int E = in_sizes[1] / 2;
  const int* row = ei;
  const int* col = ei + E;

  char* p = (char*)d_ws;
  auto alloc = [&](size_t bytes) -> void* {
    void* r = (void*)p;
    p += (bytes + 255) & ~(size_t)255;
    return r;
  };
  int*   cnt    = (int*)alloc((size_t)N * 4);
  int*   rowptr = (int*)alloc((size_t)(N + 1) * 4);
  int*   cursor = (int*)alloc((size_t)N * 4);
  int*   bsums  = (int*)alloc(1024 * 4);
  int*   boff   = (int*)alloc(1024 * 4);
  float* dinv   = (float*)alloc((size_t)N * 4);
  int*   eidx   = (int*)alloc((size_t)N * 4);
  int*   meta   = (int*)alloc(32 * 4);
  int*   perm   = (int*)alloc((size_t)N * 4);
  int2*  csr2   = (int2*)alloc((size_t)E * 8);
  unsigned short* h1    = (unsigned short*)alloc((size_t)N * 256 * 2);
  unsigned short* hrelu = (unsigned short*)alloc((size_t)N * 256 * 2);
  unsigned short* h3    = (unsigned short*)alloc((size_t)N * 64 * 2);
  unsigned short* xb  = (unsigned short*)alloc((size_t)N * 512 * 2);
  unsigned short* ewb = (unsigned short*)alloc((size_t)4 * 512 * 256 * 2);
  unsigned short* w2b = (unsigned short*)alloc((size_t)256 * 64 * 2);

  int nb = (N + 1023) / 1024;
  int gateB = (N + 15) / 16;
  int cntB = (E + 255) / 256;
  int scatB = (E + 255) / 256;
  int binB = (N + 255) / 256;

  k_init<<<(N + 255) / 256, 256, 0, stream>>>(cnt, meta, N);
  // fused + interleaved: gate (+x cast) | degree count | weight pack
  k_gate<<<gateB + cntB + 288, 256, 0, stream>>>(x, wg, eidx, meta, xb, col, cnt,
                                                 ew, ewb, w2, w2b, N, E, gateB, cntB);
  k_scanA<<<nb, 256, 0, stream>>>(cnt, rowptr, bsums, N);
  k_scanB<<<1, 256, 0, stream>>>(bsums, boff, nb);
  k_scanC<<<(N + 255) / 256, 256, 0, stream>>>(cnt, rowptr, boff, rowptr, cursor, dinv,
                                               meta, N, E);
  // fused: edge scatter | expert binscatter
  k_scatter<<<scatB + binB, 256, 0, stream>>>(row, col, cursor, dinv, csr2, E,
                                              eidx, meta, perm, N, scatB);
  int ntiles = (N + 127) / 128 + 4;
  k_gemm1<<<ntiles, 512, 0, stream>>>(xb, ewb, eb, perm, meta, h1);
  k_prop1<<<(N + 7) / 8, 256, 0, stream>>>(h1, rowptr, csr2, dinv, b1, hrelu, N);
  k_gemm2<<<(N + 127) / 128, 256, 0, stream>>>(hrelu, w2b, h3, N);
  k_prop2<<<(N + 31) / 32, 256, 0, stream>>>(h3, rowptr, csr2, dinv, b2, out, N);
}

// Round 14
// 347.593 us; speedup vs baseline: 1.0212x; 1.0126x over previous
//
#include <hip/hip_runtime.h>
#include <math.h>

typedef __bf16 bf16x8 __attribute__((ext_vector_type(8)));
typedef float f32x16 __attribute__((ext_vector_type(16)));

// ---------------- helpers ----------------
__device__ __forceinline__ unsigned short f2bf(float f) {
  union { float f; unsigned int u; } v; v.f = f;
  unsigned int r = (v.u + 0x7FFFu + ((v.u >> 16) & 1u)) >> 16;
  return (unsigned short)r;
}
__device__ __forceinline__ float bf2f(unsigned short u) {
  union { unsigned int u; float f; } v; v.u = ((unsigned int)u) << 16;
  return v.f;
}
// unpack 2 bf16 from one u32 (memory order: low half = even element)
__device__ __forceinline__ void bf2x(unsigned int u, float& lo, float& hi) {
  union { unsigned int u; float f; } a, b;
  a.u = u << 16; b.u = u & 0xFFFF0000u;
  lo = a.f; hi = b.f;
}
// async global->LDS 16B copy (global_load_lds_dwordx4)
__device__ __forceinline__ void gload16(const void* g, void* l) {
  __builtin_amdgcn_global_load_lds(
      (__attribute__((address_space(1))) void*)const_cast<void*>(g),
      (__attribute__((address_space(3))) void*)l, 16, 0, 0);
}

// ---------------- setup kernels ----------------
__global__ void k_init(int* cnt, int* meta, int N) {
  int i = blockIdx.x * blockDim.x + threadIdx.x;
  if (i < N) cnt[i] = 0;
  if (i < 32) meta[i] = 0;
}

__global__ __launch_bounds__(256) void k_scanA(const int* __restrict__ cnt,
                                               int* __restrict__ incl,
                                               int* __restrict__ bsums, int N) {
  __shared__ int s[1024];
  int base = blockIdx.x * 1024;
  #pragma unroll
  for (int t = 0; t < 4; ++t) {
    int i = threadIdx.x + t * 256;
    int idx = base + i;
    s[i] = (idx < N) ? cnt[idx] : 0;
  }
  __syncthreads();
  for (int d = 1; d < 1024; d <<= 1) {
    int v[4];
    #pragma unroll
    for (int t = 0; t < 4; ++t) {
      int i = threadIdx.x + t * 256;
      v[t] = (i >= d) ? s[i - d] : 0;
    }
    __syncthreads();
    #pragma unroll
    for (int t = 0; t < 4; ++t) {
      int i = threadIdx.x + t * 256;
      s[i] += v[t];
    }
    __syncthreads();
  }
  #pragma unroll
  for (int t = 0; t < 4; ++t) {
    int i = threadIdx.x + t * 256;
    int idx = base + i;
    if (idx < N) incl[idx] = s[i];
  }
  if (threadIdx.x == 0) bsums[blockIdx.x] = s[1023];
}

__global__ __launch_bounds__(256) void k_scanB(const int* __restrict__ bsums,
                                               int* __restrict__ boff, int nb) {
  __shared__ int s[1024];
  #pragma unroll
  for (int t = 0; t < 4; ++t) {
    int i = threadIdx.x + t * 256;
    s[i] = (i < nb) ? bsums[i] : 0;
  }
  __syncthreads();
  for (int d = 1; d < 1024; d <<= 1) {
    int v[4];
    #pragma unroll
    for (int t = 0; t < 4; ++t) {
      int i = threadIdx.x + t * 256;
      v[t] = (i >= d) ? s[i - d] : 0;
    }
    __syncthreads();
    #pragma unroll
    for (int t = 0; t < 4; ++t) {
      int i = threadIdx.x + t * 256;
      s[i] += v[t];
    }
    __syncthreads();
  }
  #pragma unroll
  for (int t = 0; t < 4; ++t) {
    int i = threadIdx.x + t * 256;
    if (i < nb) boff[i] = (i == 0) ? 0 : s[i - 1];
  }
}

// scanC + fused offs (meta hist is final: gate kernel completed before scanA)
__global__ void k_scanC(const int* __restrict__ cnt, const int* __restrict__ incl,
                        const int* __restrict__ boff, int* __restrict__ rowptr,
                        int* __restrict__ cursor, float* __restrict__ dinv,
                        int* __restrict__ meta, int N, int E) {
  int i = blockIdx.x * blockDim.x + threadIdx.x;
  if (i < N) {
    int ex = incl[i] - cnt[i] + boff[i >> 10];
    rowptr[i] = ex;
    cursor[i] = ex;
    dinv[i] = rsqrtf((float)(cnt[i] + 1));
    if (i == 0) rowptr[N] = E;
  }
  if (blockIdx.x == 0 && threadIdx.x == 0) {
    int* hist = meta;
    int* eoff = meta + 4;
    int* toff = meta + 9;
    int* ecur = meta + 14;
    int s = 0, t = 0;
    eoff[0] = 0; toff[0] = 0;
    for (int e = 0; e < 4; ++e) {
      s += hist[e];
      eoff[e + 1] = s;
      t += (hist[e] + 127) / 128;
      toff[e + 1] = t;
      ecur[e] = eoff[e];
    }
  }
}

// scatter edge -> csr2 {row, dinv[row]}; appended blocks do binscatter
__global__ __launch_bounds__(256) void k_scatter(const int* __restrict__ row,
                                                 const int* __restrict__ col,
                                                 int* __restrict__ cursor,
                                                 const float* __restrict__ dinv,
                                                 int2* __restrict__ csr2, int E,
                                                 const int* __restrict__ eidx,
                                                 int* __restrict__ meta,
                                                 int* __restrict__ perm, int N, int scatB) {
  int tid = threadIdx.x;
  if (blockIdx.x < (unsigned)scatB) {
    int e = blockIdx.x * 256 + tid;
    if (e < E) {
      int c = col[e];
      int r = row[e];
      int p = atomicAdd(&cursor[c], 1);
      csr2[p] = make_int2(r, __float_as_int(dinv[r]));
    }
    return;
  }
  // ---- binscatter (needs offs: done in k_scanC, prior launch) ----
  __shared__ int lhist[4];
  __shared__ int lbase[4];
  if (tid < 4) lhist[tid] = 0;
  __syncthreads();
  int n = (blockIdx.x - scatB) * 256 + tid;
  int e = 0, lrank = 0;
  bool valid = (n < N);
  if (valid) {
    e = eidx[n];
    lrank = atomicAdd(&lhist[e], 1);
  }
  __syncthreads();
  if (tid < 4) {
    int c = lhist[tid];
    lbase[tid] = (c > 0) ? atomicAdd(&meta[14 + tid], c) : 0;
  }
  __syncthreads();
  if (valid) perm[lbase[e] + lrank] = n;
}

// ---------------- fused gate (+bf16 cast of x) / degree-count / weight-pack ----------------
// Roles INTERLEAVED across the grid so count's atomic latency overlaps gate's streaming:
// within [0, 3*usedC): b%3==2 -> count(b/3), else gate(2*(b/3)+b%3); leftovers appended; pack last.
__global__ __launch_bounds__(256) void k_gate(const float* __restrict__ x,
                                              const float* __restrict__ wg,
                                              int* __restrict__ eidx,
                                              int* __restrict__ meta,
                                              unsigned short* __restrict__ xb,
                                              const int* __restrict__ col,
                                              int* __restrict__ cnt,
                                              const float* __restrict__ ew,
                                              unsigned short* __restrict__ ewb,
                                              const float* __restrict__ w2,
                                              unsigned short* __restrict__ w2b,
                                              int N, int E, int gateB, int cntB) {
  int tid = threadIdx.x;
  int b = blockIdx.x;
  int usedC = min(cntB, gateB / 2);
  int mix3 = 3 * usedC;
  int role, idx;                     // 0=gate 1=count 2=pack
  if (b < mix3) {
    if ((b % 3) == 2) { role = 1; idx = b / 3; }
    else              { role = 0; idx = (b / 3) * 2 + (b % 3); }
  } else {
    int r = b - mix3;
    int gLeft = gateB - 2 * usedC;
    if (r < gLeft) { role = 0; idx = 2 * usedC + r; }
    else {
      r -= gLeft;
      int cLeft = cntB - usedC;
      if (r < cLeft) { role = 1; idx = usedC + r; }
      else           { role = 2; idx = r - cLeft; }
    }
  }

  if (role == 1) {                   // ---- degree count ----
    int e = idx * 256 + tid;
    if (e < E) atomicAdd(&cnt[col[e]], 1);
    return;
  }
  if (role == 2) {                   // ---- weight pack ----
    if (idx < 256) {                 // ew: idx = e*64 + kc
      int n = tid;
      int eidx2 = idx >> 6, kc = idx & 63;
      const float* src = ew + ((size_t)eidx2 * 512 + (size_t)kc * 8) * 256 + n;
      unsigned short tmp[8];
      #pragma unroll
      for (int ke = 0; ke < 8; ++ke) tmp[ke] = f2bf(src[(size_t)ke * 256]);
      *(uint4*)(ewb + ((size_t)idx * 256 + n) * 8) = *(const uint4*)tmp;
    } else {                         // w2: kc = idx-256 in 0..31
      int kc = idx - 256;
      if (tid < 64) {
        const float* src = w2 + (size_t)kc * 8 * 64 + tid;
        unsigned short tmp[8];
        #pragma unroll
        for (int ke = 0; ke < 8; ++ke) tmp[ke] = f2bf(src[(size_t)ke * 64]);
        *(uint4*)(w2b + ((size_t)kc * 64 + tid) * 8) = *(const uint4*)tmp;
      }
    }
    return;
  }

  // ---- gating: wg transposed in LDS; 8 independent x loads up front ----
  __shared__ float wgT[4][512];
  __shared__ int lhist[4];
  if (tid < 4) lhist[tid] = 0;
  {
    int r0 = tid * 2;
    float4 wa = *(const float4*)(wg + 4 * r0);
    float4 wb = *(const float4*)(wg + 4 * (r0 + 1));
    wgT[0][r0] = wa.x; wgT[1][r0] = wa.y; wgT[2][r0] = wa.z; wgT[3][r0] = wa.w;
    wgT[0][r0 + 1] = wb.x; wgT[1][r0 + 1] = wb.y; wgT[2][r0 + 1] = wb.z; wgT[3][r0 + 1] = wb.w;
  }
  __syncthreads();
  int node = idx * 16 + (tid >> 4);
  int sl = tid & 15;
  if (node < N) {
    const float* xr = x + (size_t)node * 512;
    unsigned short* xbr = xb + (size_t)node * 512;
    float4 xv[8];
    #pragma unroll
    for (int j = 0; j < 8; ++j) xv[j] = *(const float4*)(xr + 4 * (sl + 16 * j));
    #pragma unroll
    for (int j = 0; j < 8; ++j) {
      ushort4 ov;
      ov.x = f2bf(xv[j].x); ov.y = f2bf(xv[j].y); ov.z = f2bf(xv[j].z); ov.w = f2bf(xv[j].w);
      *(ushort4*)(xbr + 4 * (sl + 16 * j)) = ov;
    }
    float l0 = 0.f, l1 = 0.f, l2 = 0.f, l3 = 0.f;
    #pragma unroll
    for (int j = 0; j < 8; ++j) {
      int k0 = 4 * (sl + 16 * j);
      float4 w0 = *(const float4*)&wgT[0][k0];
      float4 w1 = *(const float4*)&wgT[1][k0];
      float4 w2v = *(const float4*)&wgT[2][k0];
      float4 w3 = *(const float4*)&wgT[3][k0];
      l0 += xv[j].x * w0.x + xv[j].y * w0.y + xv[j].z * w0.z + xv[j].w * w0.w;
      l1 += xv[j].x * w1.x + xv[j].y * w1.y + xv[j].z * w1.z + xv[j].w * w1.w;
      l2 += xv[j].x * w2v.x + xv[j].y * w2v.y + xv[j].z * w2v.z + xv[j].w * w2v.w;
      l3 += xv[j].x * w3.x + xv[j].y * w3.y + xv[j].z * w3.z + xv[j].w * w3.w;
    }
    #pragma unroll
    for (int off = 8; off > 0; off >>= 1) {
      l0 += __shfl_xor(l0, off, 64);
      l1 += __shfl_xor(l1, off, 64);
      l2 += __shfl_xor(l2, off, 64);
      l3 += __shfl_xor(l3, off, 64);
    }
    if (sl == 0) {
      int a = 0; float best = l0;
      if (l1 > best) { best = l1; a = 1; }
      if (l2 > best) { best = l2; a = 2; }
      if (l3 > best) { best = l3; a = 3; }
      eidx[node] = a;
      atomicAdd(&lhist[a], 1);
    }
  }
  __syncthreads();
  if (tid < 4 && lhist[tid] > 0) atomicAdd(&meta[tid], lhist[tid]);
}

// ---------------- expert GEMM: bf16 MFMA 32x32x16, block tile 128x256 ----------------
__global__ __launch_bounds__(512, 2) void k_gemm1(const unsigned short* __restrict__ xb,
                                                  const unsigned short* __restrict__ ewb,
                                                  const float* __restrict__ eb,
                                                  const int* __restrict__ perm,
                                                  const int* __restrict__ meta,
                                                  unsigned short* __restrict__ h1) {
  __shared__ __align__(16) unsigned short A_lds[8192];    // [kcl 0..7][i 0..127][ke 0..7]
  __shared__ __align__(16) unsigned short B_lds[16384];   // [kcl 0..7][n 0..255][ke 0..7]
  __shared__ int sperm[128];
  const int* eoff = meta + 4;
  const int* toff = meta + 9;
  int v = blockIdx.x;
  if (v >= toff[4]) return;
  int e = 0;
  while (v >= toff[e + 1]) ++e;
  int m0 = eoff[e] + (v - toff[e]) * 128;
  int mEnd = eoff[e + 1];
  int tid = threadIdx.x;

  if (tid < 128) {
    int m = m0 + tid;
    sperm[tid] = perm[(m < mEnd) ? m : (mEnd - 1)];
  }
  __syncthreads();

  int wave = tid >> 6, lane = tid & 63;
  int wr = wave >> 2, wc = wave & 3;
  int hi = lane >> 5, lo = lane & 31;
  int r128 = tid & 127;

  f32x16 acc[2][2];
  #pragma unroll
  for (int mi = 0; mi < 2; ++mi)
    #pragma unroll
    for (int ni = 0; ni < 2; ++ni)
      #pragma unroll
      for (int r = 0; r < 16; ++r) acc[mi][ni][r] = 0.f;

  const unsigned short* arow = xb + (size_t)sperm[r128] * 512;
  int kclA = tid >> 7;  // 0..3
  const uint4* ebase = (const uint4*)(ewb + (size_t)e * 64 * 2048);

  for (int k0 = 0; k0 < 512; k0 += 64) {
    __syncthreads();  // previous chunk's compute done before LDS overwrite
    gload16(arow + k0 + kclA * 8,       &A_lds[((size_t)kclA * 128 + r128) * 8]);
    gload16(arow + k0 + (kclA + 4) * 8, &A_lds[((size_t)(kclA + 4) * 128 + r128) * 8]);
    const uint4* bsrc = ebase + (size_t)(k0 >> 3) * 256;
    gload16(bsrc + tid,        &B_lds[((size_t)0 * 512 + tid) * 8]);
    gload16(bsrc + 512 + tid,  &B_lds[((size_t)1 * 512 + tid) * 8]);
    gload16(bsrc + 1024 + tid, &B_lds[((size_t)2 * 512 + tid) * 8]);
    gload16(bsrc + 1536 + tid, &B_lds[((size_t)3 * 512 + tid) * 8]);
    __syncthreads();  // vmcnt(0) drain -> LDS ready
    #pragma unroll
    for (int s = 0; s < 4; ++s) {
      int kcl = s * 2 + hi;
      bf16x8 a0f = *(const bf16x8*)&A_lds[((size_t)kcl * 128 + wr * 64 + lo) * 8];
      bf16x8 a1f = *(const bf16x8*)&A_lds[((size_t)kcl * 128 + wr * 64 + 32 + lo) * 8];
      bf16x8 b0f = *(const bf16x8*)&B_lds[((size_t)kcl * 256 + wc * 64 + lo) * 8];
      bf16x8 b1f = *(const bf16x8*)&B_lds[((size_t)kcl * 256 + wc * 64 + 32 + lo) * 8];
      acc[0][0] = __builtin_amdgcn_mfma_f32_32x32x16_bf16(a0f, b0f, acc[0][0], 0, 0, 0);
      acc[0][1] = __builtin_amdgcn_mfma_f32_32x32x16_bf16(a0f, b1f, acc[0][1], 0, 0, 0);
      acc[1][0] = __builtin_amdgcn_mfma_f32_32x32x16_bf16(a1f, b0f, acc[1][0], 0, 0, 0);
      acc[1][1] = __builtin_amdgcn_mfma_f32_32x32x16_bf16(a1f, b1f, acc[1][1], 0, 0, 0);
    }
  }

  // epilogue: bias + scatter rows as bf16. C/D: col=lane&31, row=(reg&3)+8*(reg>>2)+4*(lane>>5)
  #pragma unroll
  for (int ni = 0; ni < 2; ++ni) {
    int col = wc * 64 + ni * 32 + lo;
    float bias = eb[e * 256 + col];
    #pragma unroll
    for (int mi = 0; mi < 2; ++mi) {
      #pragma unroll
      for (int q = 0; q < 4; ++q) {
        #pragma unroll
        for (int j = 0; j < 4; ++j) {
          int r = j + 8 * q + 4 * hi;
          int lrow = wr * 64 + mi * 32 + r;
          if (m0 + lrow < mEnd) {
            h1[(size_t)sperm[lrow] * 256 + col] = f2bf(acc[mi][ni][q * 4 + j] + bias);
          }
        }
      }
    }
  }
}

// ---------------- propagate 1 (256 feat, bf16): 32 lanes/row, 8 rows/block ----------------
__global__ __launch_bounds__(256) void k_prop1(const unsigned short* __restrict__ h1,
                                               const int* __restrict__ rowptr,
                                               const int2* __restrict__ csr2,
                                               const float* __restrict__ dinv,
                                               const float* __restrict__ bias1,
                                               unsigned short* __restrict__ hrelu, int N) {
  int tid = threadIdx.x;
  int c = blockIdx.x * 8 + (tid >> 5);
  int l = tid & 31;                        // 8 features per lane
  if (c >= N) return;
  float dc = dinv[c];
  const uint4* hr = (const uint4*)h1;      // row = 32 uint4
  uint4 sv = hr[(size_t)c * 32 + l];
  float slf = dc * dc;
  float a0, a1, a2, a3, a4, a5, a6, a7;
  {
    float lo, hi;
    bf2x(sv.x, lo, hi); a0 = lo * slf; a1 = hi * slf;
    bf2x(sv.y, lo, hi); a2 = lo * slf; a3 = hi * slf;
    bf2x(sv.z, lo, hi); a4 = lo * slf; a5 = hi * slf;
    bf2x(sv.w, lo, hi); a6 = lo * slf; a7 = hi * slf;
  }
  int jb = rowptr[c], je = rowptr[c + 1];
  int j = jb;
  #define ACC8(v, s) { float lo, hi; \
    bf2x((v).x, lo, hi); a0 += lo * (s); a1 += hi * (s); \
    bf2x((v).y, lo, hi); a2 += lo * (s); a3 += hi * (s); \
    bf2x((v).z, lo, hi); a4 += lo * (s); a5 += hi * (s); \
    bf2x((v).w, lo, hi); a6 += lo * (s); a7 += hi * (s); }
  for (; j + 7 < je; j += 8) {
    int2 rc[8];
    #pragma unroll
    for (int t = 0; t < 8; ++t) rc[t] = csr2[j + t];
    uint4 vv[8];
    #pragma unroll
    for (int t = 0; t < 8; ++t) vv[t] = hr[(size_t)rc[t].x * 32 + l];
    #pragma unroll
    for (int t = 0; t < 8; ++t) {
      float s = __int_as_float(rc[t].y) * dc;
      ACC8(vv[t], s);
    }
  }
  for (; j + 3 < je; j += 4) {
    int2 rc0 = csr2[j], rc1 = csr2[j + 1], rc2 = csr2[j + 2], rc3 = csr2[j + 3];
    uint4 v0 = hr[(size_t)rc0.x * 32 + l];
    uint4 v1 = hr[(size_t)rc1.x * 32 + l];
    uint4 v2 = hr[(size_t)rc2.x * 32 + l];
    uint4 v3 = hr[(size_t)rc3.x * 32 + l];
    float s0 = __int_as_float(rc0.y) * dc, s1 = __int_as_float(rc1.y) * dc;
    float s2 = __int_as_float(rc2.y) * dc, s3 = __int_as_float(rc3.y) * dc;
    ACC8(v0, s0); ACC8(v1, s1); ACC8(v2, s2); ACC8(v3, s3);
  }
  for (; j < je; ++j) {
    int2 rc = csr2[j];
    float s = __int_as_float(rc.y) * dc;
    uint4 v = hr[(size_t)rc.x * 32 + l];
    ACC8(v, s);
  }
  #undef ACC8
  float4 b01 = *(const float4*)(bias1 + l * 8);
  float4 b23 = *(const float4*)(bias1 + l * 8 + 4);
  a0 = fmaxf(a0 + b01.x, 0.f); a1 = fmaxf(a1 + b01.y, 0.f);
  a2 = fmaxf(a2 + b01.z, 0.f); a3 = fmaxf(a3 + b01.w, 0.f);
  a4 = fmaxf(a4 + b23.x, 0.f); a5 = fmaxf(a5 + b23.y, 0.f);
  a6 = fmaxf(a6 + b23.z, 0.f); a7 = fmaxf(a7 + b23.w, 0.f);
  uint4 ov;
  ov.x = ((unsigned int)f2bf(a1) << 16) | f2bf(a0);
  ov.y = ((unsigned int)f2bf(a3) << 16) | f2bf(a2);
  ov.z = ((unsigned int)f2bf(a5) << 16) | f2bf(a4);
  ov.w = ((unsigned int)f2bf(a7) << 16) | f2bf(a6);
  ((uint4*)hrelu)[(size_t)c * 32 + l] = ov;
}

// ---------------- GEMM2: bf16 MFMA, [N,256]x[256,64], block tile 128x64 ----------------
__global__ __launch_bounds__(256, 2) void k_gemm2(const unsigned short* __restrict__ A,
                                                  const unsigned short* __restrict__ w2b,
                                                  unsigned short* __restrict__ h3, int N) {
  __shared__ __align__(16) unsigned short B_lds[16384];  // [kc 0..31][n 0..63][ke 0..7]
  __shared__ __align__(16) unsigned short A_lds[8192];   // [kcl 0..7][i 0..127][ke 0..7]
  int tid = threadIdx.x;
  int m0 = blockIdx.x * 128;
  #pragma unroll
  for (int it = 0; it < 8; ++it)
    gload16(((const uint4*)w2b) + it * 256 + tid, &B_lds[((size_t)it * 256 + tid) * 8]);

  int wave = tid >> 6, lane = tid & 63;
  int wr = wave >> 1, wc = wave & 1;
  int hi = lane >> 5, lo = lane & 31;

  f32x16 acc[2];
  #pragma unroll
  for (int mi = 0; mi < 2; ++mi)
    #pragma unroll
    for (int r = 0; r < 16; ++r) acc[mi][r] = 0.f;

  int i = tid & 127;
  int row = m0 + i;
  if (row >= N) row = N - 1;
  const unsigned short* arow = A + (size_t)row * 256;
  int kcl0 = tid >> 7;  // 0..1

  for (int k0 = 0; k0 < 256; k0 += 64) {
    __syncthreads();  // previous compute done (and on first iter, orders vs B issue)
    #pragma unroll
    for (int t = 0; t < 4; ++t)
      gload16(arow + k0 + (kcl0 + 2 * t) * 8,
              &A_lds[((size_t)(kcl0 + 2 * t) * 128 + i) * 8]);
    __syncthreads();  // vmcnt drain: A chunk (and B on first iter) ready
    #pragma unroll
    for (int s = 0; s < 4; ++s) {
      int kcl = s * 2 + hi;
      bf16x8 a0f = *(const bf16x8*)&A_lds[((size_t)kcl * 128 + wr * 64 + lo) * 8];
      bf16x8 a1f = *(const bf16x8*)&A_lds[((size_t)kcl * 128 + wr * 64 + 32 + lo) * 8];
      bf16x8 bf = *(const bf16x8*)&B_lds[(((size_t)(k0 >> 3) + kcl) * 64 + wc * 32 + lo) * 8];
      acc[0] = __builtin_amdgcn_mfma_f32_32x32x16_bf16(a0f, bf, acc[0], 0, 0, 0);
      acc[1] = __builtin_amdgcn_mfma_f32_32x32x16_bf16(a1f, bf, acc[1], 0, 0, 0);
    }
  }

  int n = wc * 32 + lo;
  #pragma unroll
  for (int mi = 0; mi < 2; ++mi) {
    #pragma unroll
    for (int q = 0; q < 4; ++q) {
      #pragma unroll
      for (int j = 0; j < 4; ++j) {
        int r = j + 8 * q + 4 * hi;
        int orow = m0 + wr * 64 + mi * 32 + r;
        if (orow < N) h3[(size_t)orow * 64 + n] = f2bf(acc[mi][q * 4 + j]);
      }
    }
  }
}

// ---------------- propagate 2 (64 feat, bf16): 8 lanes/row, 32 rows/block ----------------
__global__ __launch_bounds__(256) void k_prop2(const unsigned short* __restrict__ h3,
                                               const int* __restrict__ rowptr,
                                               const int2* __restrict__ csr2,
                                               const float* __restrict__ dinv,
                                               const float* __restrict__ bias2,
                                               float* __restrict__ out, int N) {
  int tid = threadIdx.x;
  int c = blockIdx.x * 32 + (tid >> 3);
  int l = tid & 7;                         // 8 features per lane
  if (c >= N) return;
  float dc = dinv[c];
  const uint4* hr = (const uint4*)h3;      // row = 8 uint4
  uint4 sv = hr[(size_t)c * 8 + l];
  float slf = dc * dc;
  float a0, a1, a2, a3, a4, a5, a6, a7;
  {
    float lo, hi;
    bf2x(sv.x, lo, hi); a0 = lo * slf; a1 = hi * slf;
    bf2x(sv.y, lo, hi); a2 = lo * slf; a3 = hi * slf;
    bf2x(sv.z, lo, hi); a4 = lo * slf; a5 = hi * slf;
    bf2x(sv.w, lo, hi); a6 = lo * slf; a7 = hi * slf;
  }
  int jb = rowptr[c], je = rowptr[c + 1];
  int j = jb;
  #define ACC8(v, s) { float lo, hi; \
    bf2x((v).x, lo, hi); a0 += lo * (s); a1 += hi * (s); \
    bf2x((v).y, lo, hi); a2 += lo * (s); a3 += hi * (s); \
    bf2x((v).z, lo, hi); a4 += lo * (s); a5 += hi * (s); \
    bf2x((v).w, lo, hi); a6 += lo * (s); a7 += hi * (s); }
  for (; j + 7 < je; j += 8) {
    int2 rc[8];
    #pragma unroll
    for (int t = 0; t < 8; ++t) rc[t] = csr2[j + t];
    uint4 vv[8];
    #pragma unroll
    for (int t = 0; t < 8; ++t) vv[t] = hr[(size_t)rc[t].x * 8 + l];
    #pragma unroll
    for (int t = 0; t < 8; ++t) {
      float s = __int_as_float(rc[t].y) * dc;
      ACC8(vv[t], s);
    }
  }
  for (; j + 3 < je; j += 4) {
    int2 rc0 = csr2[j], rc1 = csr2[j + 1], rc2 = csr2[j + 2], rc3 = csr2[j + 3];
    uint4 v0 = hr[(size_t)rc0.x * 8 + l];
    uint4 v1 = hr[(size_t)rc1.x * 8 + l];
    uint4 v2 = hr[(size_t)rc2.x * 8 + l];
    uint4 v3 = hr[(size_t)rc3.x * 8 + l];
    float s0 = __int_as_float(rc0.y) * dc, s1 = __int_as_float(rc1.y) * dc;
    float s2 = __int_as_float(rc2.y) * dc, s3 = __int_as_float(rc3.y) * dc;
    ACC8(v0, s0); ACC8(v1, s1); ACC8(v2, s2); ACC8(v3, s3);
  }
  for (; j < je; ++j) {
    int2 rc = csr2[j];
    float s = __int_as_float(rc.y) * dc;
    uint4 v = hr[(size_t)rc.x * 8 + l];
    ACC8(v, s);
  }
  #undef ACC8
  float4 b01 = *(const float4*)(bias2 + l * 8);
  float4 b23 = *(const float4*)(bias2 + l * 8 + 4);
  a0 += b01.x; a1 += b01.y; a2 += b01.z; a3 += b01.w;
  a4 += b23.x; a5 += b23.y; a6 += b23.z; a7 += b23.w;
  // log_softmax over 64 features spread across 8 lanes x 8 values
  float m = fmaxf(fmaxf(fmaxf(a0, a1), fmaxf(a2, a3)), fmaxf(fmaxf(a4, a5), fmaxf(a6, a7)));
  #pragma unroll
  for (int off = 4; off > 0; off >>= 1) m = fmaxf(m, __shfl_xor(m, off, 64));
  float s = expf(a0 - m) + expf(a1 - m) + expf(a2 - m) + expf(a3 - m)
          + expf(a4 - m) + expf(a5 - m) + expf(a6 - m) + expf(a7 - m);
  #pragma unroll
  for (int off = 4; off > 0; off >>= 1) s += __shfl_xor(s, off, 64);
  float ls = m + logf(s);
  float* orow = out + (size_t)c * 64 + l * 8;
  float4 o0 = make_float4(a0 - ls, a1 - ls, a2 - ls, a3 - ls);
  float4 o1 = make_float4(a4 - ls, a5 - ls, a6 - ls, a7 - ls);
  *(float4*)orow = o0;
  *(float4*)(orow + 4) = o1;
}

// ---------------- launch ----------------
extern "C" void kernel_launch(void* const* d_in, const int* in_sizes, int n_in,
                              void* d_out, int out_size, void* d_ws, size_t ws_size,
                              hipStream_t stream) {
  const float* x  = (const float*)d_in[0];
  const int*   ei = (const int*)d_in[1];
  const float* wg = (const float*)d_in[2];
  const float* ew = (const float*)d_in[3];
  const float* eb = (const float*)d_in[4];
  const float* b1 = (const float*)d_in[5];
  const float* w2 = (const float*)d_in[6];
  const float* b2 = (const float*)d_in[7];
  float* out = (float*)d_out;

  int N = in_sizes[0] / 512;
  int E = in_sizes[1] / 2;
  const int* row = ei;
  const int* col = ei + E;

  char* p = (char*)d_ws;
  auto alloc = [&](size_t bytes) -> void* {
    void* r = (void*)p;
    p += (bytes + 255) & ~(size_t)255;
    return r;
  };
  int*   cnt    = (int*)alloc((size_t)N * 4);
  int*   rowptr = (int*)alloc((size_t)(N + 1) * 4);
  int*   cursor = (int*)alloc((size_t)N * 4);
  int*   bsums  = (int*)alloc(1024 * 4);
  int*   boff   = (int*)alloc(1024 * 4);
  float* dinv   = (float*)alloc((size_t)N * 4);
  int*   eidx   = (int*)alloc((size_t)N * 4);
  int*   meta   = (int*)alloc(32 * 4);
  int*   perm   = (int*)alloc((size_t)N * 4);
  int2*  csr2   = (int2*)alloc((size_t)E * 8);
  unsigned short* h1    = (unsigned short*)alloc((size_t)N * 256 * 2);
  unsigned short* hrelu = (unsigned short*)alloc((size_t)N * 256 * 2);
  unsigned short* h3    = (unsigned short*)alloc((size_t)N * 64 * 2);
  unsigned short* xb  = (unsigned short*)alloc((size_t)N * 512 * 2);
  unsigned short* ewb = (unsigned short*)alloc((size_t)4 * 512 * 256 * 2);
  unsigned short* w2b = (unsigned short*)alloc((size_t)256 * 64 * 2);

  int nb = (N + 1023) / 1024;
  int gateB = (N + 15) / 16;
  int cntB = (E + 255) / 256;
  int scatB = (E + 255) / 256;
  int binB = (N + 255) / 256;

  k_init<<<(N + 255) / 256, 256, 0, stream>>>(cnt, meta, N);
  // fused + interleaved: gate (+x cast) | degree count | weight pack
  k_gate<<<gateB + cntB + 288, 256, 0, stream>>>(x, wg, eidx, meta, xb, col, cnt,
                                                 ew, ewb, w2, w2b, N, E, gateB, cntB);
  k_scanA<<<nb, 256, 0, stream>>>(cnt, rowptr, bsums, N);
  k_scanB<<<1, 256, 0, stream>>>(bsums, boff, nb);
  k_scanC<<<(N + 255) / 256, 256, 0, stream>>>(cnt, rowptr, boff, rowptr, cursor, dinv,
                                               meta, N, E);
  // fused: edge scatter | expert binscatter
  k_scatter<<<scatB + binB, 256, 0, stream>>>(row, col, cursor, dinv, csr2, E,
                                              eidx, meta, perm, N, scatB);
  int ntiles = (N + 127) / 128 + 4;
  k_gemm1<<<ntiles, 512, 0, stream>>>(xb, ewb, eb, perm, meta, h1);
  k_prop1<<<(N + 7) / 8, 256, 0, stream>>>(h1, rowptr, csr2, dinv, b1, hrelu, N);
  k_gemm2<<<(N + 127) / 128, 256, 0, stream>>>(hrelu, w2b, h3, N);
  k_prop2<<<(N + 31) / 32, 256, 0, stream>>>(h3, rowptr, csr2, dinv, b2, out, N);
}